// Round 1
// baseline (442.835 us; speedup 1.0000x reference)
//
#include <hip/hip_runtime.h>
#include <math.h>

// ============================ problem constants ============================
#define NB    128
#define NS    40
#define NW    50
#define ED    200   // = 2*HW = 2*HS
#define NHW   100
#define FEAT  200
#define NC    10
#define VOCABM1 99999
#define KL2E  1.4426950408889634f

// ============================ ws memory map (bytes) ========================
// All weight blobs pre-padded: 48 rows x 464 B (28x16B bf16 weights, K padded
// to 224 with zeros, + 16 B pad unit carrying fp32 bias/ctx constants).
#define BB       22272ull
#define OFF_PGW  0ull
#define OFF_PAW  (14ull*BB)            // 311,808
#define OFF_PGS  (OFF_PAW + 5ull*BB)   // 423,168
#define OFF_PAS  (OFF_PGS + 14ull*BB)  // 734,976
#define OFF_SV   846336ull             // svec [5120][200] bf16 = 2,048,000
#define OFF_DV   2894336ull            // dvec [128][200] bf16 = 51,200
#define WS_NEED  4194304ull            // covers fp32 fallback's svec too

// LDS layout for han_kernel:
#define SLOT  24576                    // staging slot: 1536 x 16B (3 loads/thread)
#define HST   400                      // Hsh row stride (bank-stride 4 -> conflict-free)
#define HROWS 50

// ============================ helpers ======================================
typedef short bf16x8 __attribute__((ext_vector_type(8)));
typedef float f32x4  __attribute__((ext_vector_type(4)));
typedef unsigned u32x4 __attribute__((ext_vector_type(4)));

__device__ __forceinline__ unsigned short f2bf(float f) {
    unsigned int u = __float_as_uint(f);
    u += 0x7fffu + ((u >> 16) & 1u);          // RNE
    return (unsigned short)(u >> 16);
}
__device__ __forceinline__ float bf2f(short s) {
    return __uint_as_float(((unsigned int)(unsigned short)s) << 16);
}
__device__ __forceinline__ float frcp(float x) { return __builtin_amdgcn_rcpf(x); }
#if __has_builtin(__builtin_amdgcn_exp2f)
__device__ __forceinline__ float fexp2(float x){ return __builtin_amdgcn_exp2f(x); }
#else
__device__ __forceinline__ float fexp2(float x){ return exp2f(x); }
#endif
__device__ __forceinline__ float fsig(float x) { return frcp(1.f + __expf(-x)); }
__device__ __forceinline__ float ftanh(float x){ return 1.f - 2.f*frcp(1.f + __expf(2.f*x)); }

// HW packed f32->bf16 (RNE), 1 inst per 2 values (no builtin on gfx950; T12/m240)
__device__ __forceinline__ unsigned cvtpk(float lo, float hi) {
    unsigned r;
    asm("v_cvt_pk_bf16_f32 %0, %1, %2" : "=v"(r) : "v"(lo), "v"(hi));
    return r;
}

// async global->LDS, 16B per lane; LDS dst = wave-uniform base + lane*16.
__device__ __forceinline__ void gld16(const void* g, void* l) {
    __builtin_amdgcn_global_load_lds(
        (const __attribute__((address_space(1))) void*)g,
        (__attribute__((address_space(3))) void*)l, 16, 0, 0);
}

// staging: 1536 16B units, uniform 3 loads per thread (512 thr) so vmcnt
// counting is wave-uniform. Reads 24,576 B from src (2,304 B overrun past the
// 22,272-B blob stays inside the packed-ws region; the excess LDS bytes are
// never read).
__device__ __forceinline__ void stageBlob3(char* __restrict__ dst,
                                           const char* __restrict__ src, int tid)
{
    gld16(src + (size_t)tid * 16,           dst + (size_t)tid * 16);
    gld16(src + (size_t)(512 + tid) * 16,   dst + (size_t)(512 + tid) * 16);
    gld16(src + (size_t)(1024 + tid) * 16,  dst + (size_t)(1024 + tid) * 16);
}

__device__ __forceinline__ bf16x8 pack8(float4 a, float4 b) {
    u32x4 t;
    t[0] = cvtpk(a.x, a.y); t[1] = cvtpk(a.z, a.w);
    t[2] = cvtpk(b.x, b.y); t[3] = cvtpk(b.z, b.w);
    return __builtin_bit_cast(bf16x8, t);
}

// ============================ P1: weight packing ===========================
// 38 blocks: 0..13 word GRU (dir*7+c), 14..18 word attn, 19..32 sent GRU,
// 33..37 sent attn. GRU pad rows 0..15: [bR'(16) bZ'(16) bN2(16) hN2(16)],
// bR' = -K(bihR+bhhR), bZ' = K(bihZ+bhhZ), bN2 = 2K*bihN, hN2 = 2K*bhhN.
// Attn pad rows 0..11: ab2 = 2K*ab; rows 12..23: cx2n = -2*cx.
__global__ void pack_kernel(
    const float* __restrict__ wWf, const float* __restrict__ wbif, const float* __restrict__ wbhf,
    const float* __restrict__ wWb, const float* __restrict__ wbib, const float* __restrict__ wbhb,
    const float* __restrict__ waW, const float* __restrict__ wab, const float* __restrict__ wactx,
    const float* __restrict__ sWf, const float* __restrict__ sbif, const float* __restrict__ sbhf,
    const float* __restrict__ sWb, const float* __restrict__ sbib, const float* __restrict__ sbhb,
    const float* __restrict__ saW, const float* __restrict__ sab, const float* __restrict__ sactx,
    char* __restrict__ ws)
{
    const int b = blockIdx.x, tid = threadIdx.x;
    const bool word = b < 19;
    const int lb = word ? b : b - 19;
    char* blob;
    if (lb < 14) blob = ws + (word ? OFF_PGW : OFF_PGS) + (size_t)lb * BB;
    else         blob = ws + (word ? OFF_PAW : OFF_PAS) + (size_t)(lb - 14) * BB;

    for (int i = tid; i < (int)(BB / 4); i += 256) ((unsigned*)blob)[i] = 0u;
    __syncthreads();

    unsigned short* w16 = (unsigned short*)blob;
    if (lb < 14) {
        const int dir = lb / 7, c = lb % 7;
        const float* W   = word ? (dir ? wWb : wWf) : (dir ? sWb : sWf);
        const float* bih = word ? (dir ? wbib : wbif) : (dir ? sbib : sbif);
        const float* bhh = word ? (dir ? wbhb : wbhf) : (dir ? sbhb : sbhf);
        for (int e = tid; e < 48 * 200; e += 256) {
            const int row = e / 200, k = e - row * 200;
            const int gate = row >> 4, j = c * 16 + (row & 15);
            if (j < NHW) w16[row * 232 + k] = f2bf(W[(size_t)(gate * NHW + j) * ED + k]);
        }
        if (tid < 64) {
            const int sect = tid >> 4, j = c * 16 + (tid & 15);
            float v = 0.f;
            if (j < NHW) {
                if (sect == 0)      v = -KL2E * (bih[j] + bhh[j]);
                else if (sect == 1) v =  KL2E * (bih[NHW + j] + bhh[NHW + j]);
                else if (sect == 2) v = 2.f * KL2E * bih[2 * NHW + j];
                else                v = 2.f * KL2E * bhh[2 * NHW + j];
            }
            ((float*)(blob + (size_t)(tid >> 2) * 464 + 448))[tid & 3] = v;
        }
    } else {
        const int cb = lb - 14;
        const float* W  = word ? waW : saW;
        const float* ab = word ? wab : sab;
        const float* cx = word ? wactx : sactx;
        for (int e = tid; e < 48 * 200; e += 256) {
            const int row = e / 200, k = e - row * 200;
            const int d = cb * 48 + row;
            if (d < FEAT) w16[row * 232 + k] = f2bf(W[(size_t)d * FEAT + k]);
        }
        if (tid < 48) {
            const int d = cb * 48 + tid;
            float ab2 = 0.f, cxn = 0.f;
            if (d < FEAT) { ab2 = 2.f * KL2E * ab[d]; cxn = -2.f * cx[d]; }
            ((float*)(blob + (size_t)(tid >> 2) * 464 + 448))[tid & 3] = ab2;
            ((float*)(blob + (size_t)(12 + (tid >> 2)) * 464 + 448))[tid & 3] = cxn;
        }
    }
}

// ============================ fused HAN stage kernel =======================
// Block = 4 groups (sentences/docs), 512 thr = 8 waves (2 per group, Mt=2).
// v2 pipeline: 3-slot staging ring with counted s_waitcnt vmcnt(3) + raw
// s_barrier per stage (never vmcnt(0) in the loop) -> blob s+2 stays in
// flight across the barrier, removing the per-stage drain stall.
// H: [4][50][400] bf16 in LDS (bank-stride 4, conflict-free; invalid items
// skip write / zero-fill on read). sc/al/part alias slot 0 (dead post-loop;
// dummy late stagings only touch slots 1-2).
template<bool WORD>
__global__ __launch_bounds__(512, 2) void han_kernel(
    const int* __restrict__ xtok,
    const void* __restrict__ Ain,
    const char* __restrict__ gpk,    // 14 GRU blobs
    const char* __restrict__ apk,    // 5 attn blobs
    const int nvalid,                // 50 / 40
    unsigned short* __restrict__ Out)
{
    __shared__ __align__(16) char smem[3 * SLOT + 4 * HROWS * HST];  // 153,728
    char*  bufs  = smem;                          // 3 x 24,576
    char*  Hsh   = smem + 3 * SLOT;               // [4][50][400]
    float* sc_sh = (float*)(smem);                // [4][64]   (slot-0 alias)
    float* al_sh = (float*)(smem + 1024);         // [4][64]   (slot-0 alias)
    float* part  = (float*)(smem + 2048);         // [4][2][224] (slot-0 alias)

    const int tid  = threadIdx.x;
    const int lane = tid & 63, wv = tid >> 6;
    const int sent = wv >> 1, half = wv & 1;
    const int ln15 = lane & 15, q = lane >> 4;
    const long g   = (long)blockIdx.x * 4 + sent;
    char* Hme = Hsh + (size_t)sent * (HROWS * HST);

    // ---- prologue staging: slots 0,1 (6 loads/thread in flight) ----
    stageBlob3(bufs,        gpk,      tid);
    stageBlob3(bufs + SLOT, gpk + BB, tid);

    // ---- A fragments (overlaps staging latency) ----
    bf16x8 af[2][7];
    if (WORD) {
        const float* emb = (const float*)Ain;
        #pragma unroll
        for (int Mt = 0; Mt < 2; ++Mt) {
            const int item = half * 32 + Mt * 16 + ln15;
            int tok = VOCABM1;                       // padding row: all zeros
            if (item < nvalid) tok = xtok[g * nvalid + item];
            const float4* rp = (const float4*)(emb + (long)tok * ED);
            #pragma unroll
            for (int kc = 0; kc < 6; ++kc)
                af[Mt][kc] = pack8(rp[kc * 8 + q * 2], rp[kc * 8 + q * 2 + 1]);
            af[Mt][6] = (q == 0) ? pack8(rp[48], rp[49]) : (bf16x8)(short)0;
        }
    } else {
        const char* sv = (const char*)Ain;
        #pragma unroll
        for (int Mt = 0; Mt < 2; ++Mt) {
            const int item = half * 32 + Mt * 16 + ln15;
            const int ic = item < nvalid ? item : nvalid - 1;
            const char* rp = sv + (g * nvalid + ic) * 400;
            #pragma unroll
            for (int kc = 0; kc < 7; ++kc) {
                bf16x8 v = (bf16x8)(short)0;
                if (item < nvalid && (kc < 6 || q == 0))
                    v = *(const bf16x8*)(rp + kc * 64 + q * 16);
                af[Mt][kc] = v;
            }
        }
    }

    // wait slot 0 resident (slot 1's 3 loads may remain in flight), align waves
    asm volatile("s_waitcnt vmcnt(3)" ::: "memory");
    __builtin_amdgcn_s_barrier();

    bf16x8 hf[2][7];
    float sacc[2][4] = {{0.f}};

    for (int s = 0; s < 19; ++s) {
        // issue blob s+2 into slot (s+2)%3. Safe: the barrier ending stage s-1
        // guarantees no wave still reads slot (s-1)%3 == (s+2)%3. Clamp keeps
        // the per-thread load count uniform for vmcnt (dummy restage of blob
        // 18 lands in slots 1/2 only).
        {
            const int t = (s + 2 <= 18) ? (s + 2) : 18;
            const char* nb = (t < 14) ? gpk + (size_t)t * BB
                                      : apk + (size_t)(t - 14) * BB;
            stageBlob3(bufs + (size_t)((s + 2) % 3) * SLOT, nb, tid);
        }
        char* cur = bufs + (size_t)(s % 3) * SLOT;

        if (s < 14) {
            // ---- GRU chunk: units [cc*16, +16) of direction dir ----
            f32x4 a0[2] = {}, a1[2] = {}, a2[2] = {};
            #pragma unroll
            for (int kc = 0; kc < 7; ++kc) {
                const bf16x8 b0 = *(const bf16x8*)(cur + (size_t)(0  + ln15) * 464 + kc * 64 + q * 16);
                const bf16x8 b1 = *(const bf16x8*)(cur + (size_t)(16 + ln15) * 464 + kc * 64 + q * 16);
                const bf16x8 b2 = *(const bf16x8*)(cur + (size_t)(32 + ln15) * 464 + kc * 64 + q * 16);
                #pragma unroll
                for (int Mt = 0; Mt < 2; ++Mt) {
                    a0[Mt] = __builtin_amdgcn_mfma_f32_16x16x32_bf16(b0, af[Mt][kc], a0[Mt], 0, 0, 0);
                    a1[Mt] = __builtin_amdgcn_mfma_f32_16x16x32_bf16(b1, af[Mt][kc], a1[Mt], 0, 0, 0);
                    a2[Mt] = __builtin_amdgcn_mfma_f32_16x16x32_bf16(b2, af[Mt][kc], a2[Mt], 0, 0, 0);
                }
            }
            const int dir = s / 7, cc = s - dir * 7;
            if (cc * 16 + q * 4 < NHW) {
                const f32x4 bR = *(const f32x4*)(cur + (size_t)(0  + q) * 464 + 448);
                const f32x4 bZ = *(const f32x4*)(cur + (size_t)(4  + q) * 464 + 448);
                const f32x4 bN = *(const f32x4*)(cur + (size_t)(8  + q) * 464 + 448);
                const f32x4 hN = *(const f32x4*)(cur + (size_t)(12 + q) * 464 + 448);
                const int ub = dir * NHW + cc * 16 + q * 4;
                #pragma unroll
                for (int Mt = 0; Mt < 2; ++Mt) {
                    const int item = half * 32 + Mt * 16 + ln15;
                    float h[4];
                    #pragma unroll
                    for (int rg = 0; rg < 4; ++rg) {
                        const float r  = frcp(1.f + fexp2(fmaf(a0[Mt][rg], -KL2E, bR[rg])));
                        const float zc = frcp(1.f + fexp2(fmaf(a1[Mt][rg],  KL2E, bZ[rg])));
                        const float t  = frcp(1.f + fexp2(fmaf(a2[Mt][rg], 2.f * KL2E,
                                                  fmaf(r, hN[rg], bN[rg]))));
                        h[rg] = zc * (1.f - 2.f * t);
                    }
                    if (item < nvalid) {
                        uint2 o; o.x = cvtpk(h[0], h[1]); o.y = cvtpk(h[2], h[3]);
                        *(uint2*)(Hme + (size_t)item * HST + ub * 2) = o;
                    }
                }
            }
        } else {
            // ---- attention score chunk ----
            if (s == 14) {   // H rows are wave-own; same-wave ds ordering via lgkmcnt
                #pragma unroll
                for (int Mt = 0; Mt < 2; ++Mt) {
                    const int item = half * 32 + Mt * 16 + ln15;
                    #pragma unroll
                    for (int kc = 0; kc < 7; ++kc) {
                        bf16x8 v = (bf16x8)(short)0;
                        if (item < nvalid && (kc < 6 || q == 0))
                            v = *(const bf16x8*)(Hme + (size_t)item * HST + kc * 64 + q * 16);
                        hf[Mt][kc] = v;
                    }
                }
            }
            f32x4 ac[2][3] = {};
            #pragma unroll
            for (int kc = 0; kc < 7; ++kc) {
                const bf16x8 b0 = *(const bf16x8*)(cur + (size_t)(0  + ln15) * 464 + kc * 64 + q * 16);
                const bf16x8 b1 = *(const bf16x8*)(cur + (size_t)(16 + ln15) * 464 + kc * 64 + q * 16);
                const bf16x8 b2 = *(const bf16x8*)(cur + (size_t)(32 + ln15) * 464 + kc * 64 + q * 16);
                #pragma unroll
                for (int Mt = 0; Mt < 2; ++Mt) {
                    ac[Mt][0] = __builtin_amdgcn_mfma_f32_16x16x32_bf16(hf[Mt][kc], b0, ac[Mt][0], 0, 0, 0);
                    ac[Mt][1] = __builtin_amdgcn_mfma_f32_16x16x32_bf16(hf[Mt][kc], b1, ac[Mt][1], 0, 0, 0);
                    ac[Mt][2] = __builtin_amdgcn_mfma_f32_16x16x32_bf16(hf[Mt][kc], b2, ac[Mt][2], 0, 0, 0);
                }
            }
            // tanh(u)·cx = cx - 2·cx·sig-like; constant Σcx dropped (softmax-
            // shift-invariant): sacc += u * cx2n, u = 1/(1+exp2(2K·acc + ab2))
            #pragma unroll
            for (int Nt = 0; Nt < 3; ++Nt) {
                const int bo = 4 * (Nt * 16 + ln15);
                const float ab2 = *(const float*)(cur + (size_t)(bo >> 4) * 464 + 448 + (bo & 15));
                const int co = 192 + bo;
                const float cxn = *(const float*)(cur + (size_t)(co >> 4) * 464 + 448 + (co & 15));
                #pragma unroll
                for (int Mt = 0; Mt < 2; ++Mt)
                    #pragma unroll
                    for (int rg = 0; rg < 4; ++rg) {
                        const float u = frcp(1.f + fexp2(fmaf(ac[Mt][Nt][rg], 2.f * KL2E, ab2)));
                        sacc[Mt][rg] = fmaf(u, cxn, sacc[Mt][rg]);
                    }
            }
        }
        // counted wait: blob s+1 resident (issued a full stage ago); blob s+2's
        // 3 loads stay in flight across the barrier. Never vmcnt(0) here.
        asm volatile("s_waitcnt vmcnt(3)" ::: "memory");
        __builtin_amdgcn_s_barrier();
    }

    // ---- reduce scores over the 16 d-lanes; park per word-row ----
    #pragma unroll
    for (int Mt = 0; Mt < 2; ++Mt)
        #pragma unroll
        for (int rg = 0; rg < 4; ++rg) {
            float v = sacc[Mt][rg];
            v += __shfl_xor(v, 1); v += __shfl_xor(v, 2);
            v += __shfl_xor(v, 4); v += __shfl_xor(v, 8);
            sacc[Mt][rg] = v;
        }
    // slot 0 (sc/al/part alias) is dead: its last reads were stage 18,
    // retired by the loop's final barrier; late dummy stagings hit slots 1/2.
    if (ln15 == 0) {
        #pragma unroll
        for (int Mt = 0; Mt < 2; ++Mt)
            #pragma unroll
            for (int rg = 0; rg < 4; ++rg)
                sc_sh[sent * 64 + half * 32 + Mt * 16 + q * 4 + rg] = sacc[Mt][rg];
    }
    __syncthreads();

    // ---- per-group softmax over 64 padded rows (exp2-scaled) ----
    {
        const float sv0 = (lane < nvalid) ? sc_sh[sent * 64 + lane] : -1e30f;
        float m = sv0;
        m = fmaxf(m, __shfl_xor(m, 1));  m = fmaxf(m, __shfl_xor(m, 2));
        m = fmaxf(m, __shfl_xor(m, 4));  m = fmaxf(m, __shfl_xor(m, 8));
        m = fmaxf(m, __shfl_xor(m, 16)); m = fmaxf(m, __shfl_xor(m, 32));
        const float e = (lane < nvalid) ? fexp2((sv0 - m) * KL2E) : 0.f;
        float ss = e;
        ss += __shfl_xor(ss, 1);  ss += __shfl_xor(ss, 2);
        ss += __shfl_xor(ss, 4);  ss += __shfl_xor(ss, 8);
        ss += __shfl_xor(ss, 16); ss += __shfl_xor(ss, 32);
        if (half == 0) al_sh[sent * 64 + lane] = e * frcp(ss);
    }
    __syncthreads();

    // ---- pooling straight from hf fragments ----
    {
        const float aM0 = al_sh[sent * 64 + half * 32 + ln15];
        const float aM1 = al_sh[sent * 64 + half * 32 + 16 + ln15];
        #pragma unroll
        for (int kc = 0; kc < 7; ++kc) {
            float p[8];
            #pragma unroll
            for (int j = 0; j < 8; ++j)
                p[j] = aM0 * bf2f(hf[0][kc][j]) + aM1 * bf2f(hf[1][kc][j]);
            #pragma unroll
            for (int j = 0; j < 8; ++j) {
                p[j] += __shfl_xor(p[j], 1); p[j] += __shfl_xor(p[j], 2);
                p[j] += __shfl_xor(p[j], 4); p[j] += __shfl_xor(p[j], 8);
            }
            if (ln15 == 0) {
                float* dst = part + (size_t)(sent * 2 + half) * 224 + kc * 32 + q * 8;
                f32x4 v0 = {p[0], p[1], p[2], p[3]};
                f32x4 v1 = {p[4], p[5], p[6], p[7]};
                *(f32x4*)dst = v0; *(f32x4*)(dst + 4) = v1;
            }
        }
    }
    __syncthreads();

    // ---- combine halves, write pooled bf16 rows ----
    if (tid < 200) {
        const int sl = tid / 50, i = tid - sl * 50;     // i*4 = k0 < 200
        const float* pa = part + (size_t)(sl * 2) * 224 + i * 4;
        const float* pb = part + (size_t)(sl * 2 + 1) * 224 + i * 4;
        uint2 o;
        o.x = cvtpk(pa[0] + pb[0], pa[1] + pb[1]);
        o.y = cvtpk(pa[2] + pb[2], pa[3] + pb[3]);
        *(uint2*)(Out + ((long)blockIdx.x * 4 + sl) * 200 + i * 4) = o;
    }
}

// ============================ classifier + log_softmax =====================
__global__ void cls_kernel(const unsigned short* __restrict__ dvec,
                           const float* __restrict__ fcW, const float* __restrict__ fcb,
                           float* __restrict__ out)
{
    const int doc = blockIdx.x, lane = threadIdx.x;  // 64 threads
    const int c = lane & 15, part = lane >> 4;
    const int cs = (c < NC) ? c : 0;
    float acc = (part == 0 && c < NC) ? fcb[c] : 0.f;
    for (int i = 0; i < 50; ++i) {
        const int k = part * 50 + i;
        const float a = bf2f((short)dvec[(size_t)doc * 200 + k]);
        acc += a * ((c < NC) ? fcW[(size_t)cs * 200 + k] : 0.f);
    }
    acc += __shfl_xor(acc, 16); acc += __shfl_xor(acc, 32);
    const float lg = (c < NC) ? acc : -1e30f;
    float m = lg;
    m = fmaxf(m, __shfl_xor(m, 1)); m = fmaxf(m, __shfl_xor(m, 2));
    m = fmaxf(m, __shfl_xor(m, 4)); m = fmaxf(m, __shfl_xor(m, 8));
    const float e = (c < NC) ? __expf(lg - m) : 0.f;
    float ss = e;
    ss += __shfl_xor(ss, 1); ss += __shfl_xor(ss, 2);
    ss += __shfl_xor(ss, 4); ss += __shfl_xor(ss, 8);
    const float lse = m + __logf(ss);
    if (lane < NC) out[(size_t)doc * NC + lane] = lg - lse;
}

// ======================================================================
// Fallback fp32 path — used only if ws_size < WS_NEED.
// ======================================================================
template<int NWRD, int WT>
__device__ __forceinline__ void encode_block(
    float* __restrict__ e_sh, float* __restrict__ h_sh, float* __restrict__ sc_sh,
    const float* __restrict__ Wf, const float* __restrict__ bihf, const float* __restrict__ bhhf,
    const float* __restrict__ Wb, const float* __restrict__ bihb, const float* __restrict__ bhhb,
    const float* __restrict__ aW, const float* __restrict__ ab, const float* __restrict__ actx,
    int tid)
{
    constexpr int WG = NWRD / WT;
    for (int item = tid; item < FEAT * WG; item += 256) {
        const int unit = item % FEAT, wg = item / FEAT;
        const int dir = unit / NHW, j = unit - dir * NHW;
        const float* Wd  = dir ? Wb : Wf;
        const float* bih = dir ? bihb : bihf;
        const float* bhh = dir ? bhhb : bhhf;
        const float4* rowR = (const float4*)(Wd + (size_t)j * ED);
        const float4* rowZ = (const float4*)(Wd + (size_t)(NHW + j) * ED);
        const float4* rowN = (const float4*)(Wd + (size_t)(2 * NHW + j) * ED);
        float aR[WT], aZ[WT], aN[WT];
        #pragma unroll
        for (int t = 0; t < WT; ++t) { aR[t] = 0.f; aZ[t] = 0.f; aN[t] = 0.f; }
        const int w0 = wg * WT;
        #pragma unroll 1
        for (int k4 = 0; k4 < ED / 4; ++k4) {
            const float4 wr = rowR[k4], wz = rowZ[k4], wn = rowN[k4];
            #pragma unroll
            for (int t = 0; t < WT; ++t) {
                const float4 e = *(const float4*)(e_sh + (w0 + t) * ED + k4 * 4);
                aR[t] += wr.x*e.x + wr.y*e.y + wr.z*e.z + wr.w*e.w;
                aZ[t] += wz.x*e.x + wz.y*e.y + wz.z*e.z + wz.w*e.w;
                aN[t] += wn.x*e.x + wn.y*e.y + wn.z*e.z + wn.w*e.w;
            }
        }
        const float bR = bih[j] + bhh[j], bZ = bih[NHW+j] + bhh[NHW+j];
        const float bN = bih[2*NHW+j], hN = bhh[2*NHW+j];
        #pragma unroll
        for (int t = 0; t < WT; ++t) {
            const float r = fsig(aR[t] + bR), z = fsig(aZ[t] + bZ);
            const float n = ftanh(aN[t] + bN + r * hN);
            h_sh[(w0 + t) * FEAT + unit] = (1.f - z) * n;
        }
    }
    __syncthreads();
    for (int item = tid; item < FEAT * WG; item += 256) {
        const int d = item % FEAT, wg = item / FEAT;
        const float4* row = (const float4*)(aW + (size_t)d * FEAT);
        float acc[WT];
        #pragma unroll
        for (int t = 0; t < WT; ++t) acc[t] = 0.f;
        const int w0 = wg * WT;
        #pragma unroll 1
        for (int k4 = 0; k4 < FEAT / 4; ++k4) {
            const float4 wv = row[k4];
            #pragma unroll
            for (int t = 0; t < WT; ++t) {
                const float4 h = *(const float4*)(h_sh + (w0 + t) * FEAT + k4 * 4);
                acc[t] += wv.x*h.x + wv.y*h.y + wv.z*h.z + wv.w*h.w;
            }
        }
        const float bb = ab[d], cc = actx[d];
        #pragma unroll
        for (int t = 0; t < WT; ++t)
            e_sh[d * NWRD + (w0 + t)] = ftanh(acc[t] + bb) * cc;
    }
    __syncthreads();
    if (tid < NWRD) {
        float s = 0.f;
        for (int d = 0; d < FEAT; ++d) s += e_sh[d * NWRD + tid];
        sc_sh[tid] = s;
    }
    __syncthreads();
    if (tid == 0) {
        float m = -1e30f;
        for (int w = 0; w < NWRD; ++w) m = fmaxf(m, sc_sh[w]);
        float s = 0.f;
        for (int w = 0; w < NWRD; ++w) { const float ev = __expf(sc_sh[w] - m); sc_sh[w] = ev; s += ev; }
        const float inv = 1.f / s;
        for (int w = 0; w < NWRD; ++w) sc_sh[w] *= inv;
    }
    __syncthreads();
}

__global__ __launch_bounds__(256) void word_kernel_f32(
    const int* __restrict__ x, const float* __restrict__ emb,
    const float* __restrict__ Wf, const float* __restrict__ bihf, const float* __restrict__ bhhf,
    const float* __restrict__ Wb, const float* __restrict__ bihb, const float* __restrict__ bhhb,
    const float* __restrict__ waW, const float* __restrict__ wab, const float* __restrict__ wactx,
    float* __restrict__ svec)
{
    __shared__ __align__(16) float e_sh[NW * ED];
    __shared__ __align__(16) float h_sh[NW * FEAT];
    __shared__ float sc_sh[NW];
    const int sent = blockIdx.x, tid = threadIdx.x;
    const int* xr = x + (size_t)sent * NW;
    for (int i = tid * 4; i < NW * ED; i += 256 * 4) {
        const int w = i / ED, k = i - w * ED;
        *(float4*)(e_sh + i) = *(const float4*)(emb + (size_t)xr[w] * ED + k);
    }
    __syncthreads();
    encode_block<NW, 25>(e_sh, h_sh, sc_sh, Wf, bihf, bhhf, Wb, bihb, bhhb, waW, wab, wactx, tid);
    if (tid < FEAT) {
        float a = 0.f;
        #pragma unroll 1
        for (int w = 0; w < NW; ++w) a += sc_sh[w] * h_sh[w * FEAT + tid];
        svec[(size_t)sent * FEAT + tid] = a;
    }
}

__global__ __launch_bounds__(256) void sent_kernel_f32(
    const float* __restrict__ svec,
    const float* __restrict__ Wf, const float* __restrict__ bihf, const float* __restrict__ bhhf,
    const float* __restrict__ Wb, const float* __restrict__ bihb, const float* __restrict__ bhhb,
    const float* __restrict__ saW, const float* __restrict__ sab, const float* __restrict__ sactx,
    const float* __restrict__ fcW, const float* __restrict__ fcb,
    float* __restrict__ out)
{
    __shared__ __align__(16) float e_sh[NS * ED];
    __shared__ __align__(16) float h_sh[NS * FEAT];
    __shared__ float sc_sh[NS];
    __shared__ float dvec_sh[FEAT];
    __shared__ float logit_sh[NC];
    __shared__ float lse_sh;
    const int b = blockIdx.x, tid = threadIdx.x;
    const float* src = svec + (size_t)b * NS * FEAT;
    for (int i = tid * 4; i < NS * FEAT; i += 256 * 4)
        *(float4*)(e_sh + i) = *(const float4*)(src + i);
    __syncthreads();
    encode_block<NS, 20>(e_sh, h_sh, sc_sh, Wf, bihf, bhhf, Wb, bihb, bhhb, saW, sab, sactx, tid);
    if (tid < FEAT) {
        float a = 0.f;
        #pragma unroll 1
        for (int s = 0; s < NS; ++s) a += sc_sh[s] * h_sh[s * FEAT + tid];
        dvec_sh[tid] = a;
    }
    __syncthreads();
    if (tid < NC) {
        float a = fcb[tid];
        const float* row = fcW + (size_t)tid * FEAT;
        for (int k = 0; k < FEAT; ++k) a += row[k] * dvec_sh[k];
        logit_sh[tid] = a;
    }
    __syncthreads();
    if (tid == 0) {
        float m = -1e30f;
        for (int c = 0; c < NC; ++c) m = fmaxf(m, logit_sh[c]);
        float s = 0.f;
        for (int c = 0; c < NC; ++c) s += __expf(logit_sh[c] - m);
        lse_sh = m + logf(s);
    }
    __syncthreads();
    if (tid < NC) out[(size_t)b * NC + tid] = logit_sh[tid] - lse_sh;
}

// ============================ launch =======================================
extern "C" void kernel_launch(void* const* d_in, const int* in_sizes, int n_in,
                              void* d_out, int out_size, void* d_ws, size_t ws_size,
                              hipStream_t stream)
{
    const int*   x     = (const int*)d_in[0];
    const float* emb   = (const float*)d_in[1];
    const float* wWf   = (const float*)d_in[2];
    const float* wbif  = (const float*)d_in[3];
    const float* wbhf  = (const float*)d_in[4];
    const float* wWb   = (const float*)d_in[5];
    const float* wbib  = (const float*)d_in[6];
    const float* wbhb  = (const float*)d_in[7];
    const float* waW   = (const float*)d_in[8];
    const float* wab   = (const float*)d_in[9];
    const float* wactx = (const float*)d_in[10];
    const float* sWf   = (const float*)d_in[11];
    const float* sbif  = (const float*)d_in[12];
    const float* sbhf  = (const float*)d_in[13];
    const float* sWb   = (const float*)d_in[14];
    const float* sbib  = (const float*)d_in[15];
    const float* sbhb  = (const float*)d_in[16];
    const float* saW   = (const float*)d_in[17];
    const float* sab   = (const float*)d_in[18];
    const float* sactx = (const float*)d_in[19];
    const float* fcW   = (const float*)d_in[20];
    const float* fcb   = (const float*)d_in[21];
    float* out = (float*)d_out;

    if (ws_size < WS_NEED) {
        float* svec = (float*)d_ws;
        word_kernel_f32<<<NB * NS, 256, 0, stream>>>(
            x, emb, wWf, wbif, wbhf, wWb, wbib, wbhb, waW, wab, wactx, svec);
        sent_kernel_f32<<<NB, 256, 0, stream>>>(
            svec, sWf, sbif, sbhf, sWb, sbib, sbhb, saW, sab, sactx, fcW, fcb, out);
        return;
    }

    char* ws = (char*)d_ws;
    unsigned short* svec = (unsigned short*)(ws + OFF_SV);
    unsigned short* dvec = (unsigned short*)(ws + OFF_DV);

    pack_kernel<<<38, 256, 0, stream>>>(
        wWf, wbif, wbhf, wWb, wbib, wbhb, waW, wab, wactx,
        sWf, sbif, sbhf, sWb, sbib, sbhb, saW, sab, sactx, ws);

    // word stage: 5120 sentences / 4 per block
    han_kernel<true><<<NB * NS / 4, 512, 0, stream>>>(
        x, emb, ws + OFF_PGW, ws + OFF_PAW, NW, svec);

    // sentence stage: 128 docs / 4 per block
    han_kernel<false><<<NB / 4, 512, 0, stream>>>(
        nullptr, svec, ws + OFF_PGS, ws + OFF_PAS, NS, dvec);

    cls_kernel<<<NB, 64, 0, stream>>>(dvec, fcW, fcb, out);
}

// Round 3
// 400.520 us; speedup vs baseline: 1.1056x; 1.1056x over previous
//
#include <hip/hip_runtime.h>
#include <math.h>

// ============================ problem constants ============================
#define NB    128
#define NS    40
#define NW    50
#define ED    200   // = 2*HW = 2*HS
#define NHW   100
#define FEAT  200
#define NC    10
#define VOCABM1 99999
#define KL2E  1.4426950408889634f

// ============================ ws memory map (bytes) ========================
// Blobs: 48 rows x 432 B (25x16B bf16 weights K<=200, +16 B fp32-bias unit at
// byte 400, +16 B zero pad). Blob = 20,736 B.
// NOTE: b128 weight reads must NOT touch bytes 400..416 (fp32 bias bits are
// not valid bf16 -> 0*NaN poisons MFMA). kc==6 reads are q==0 only.
#define BB       20736ull
#define OFF_PGW  0ull
#define OFF_PAW  (14ull*BB)            // 290,304
#define OFF_PGS  (OFF_PAW + 5ull*BB)   // 393,984
#define OFF_PAS  (OFF_PGS + 14ull*BB)  // 684,288
#define OFF_SV   846336ull             // svec [5120][200] bf16 = 2,048,000
#define OFF_DV   2894336ull            // dvec [128][200] bf16 = 51,200
#define WS_NEED  4194304ull            // covers fp32 fallback's svec too

// LDS layout for han_kernel (total 81,472 -> rounds to 81,920 = 2 blocks/CU):
#define SLOT   20736                   // staging slot: 1296 x 16B
#define HST    400                     // Hsh row stride (bank-stride 4)
#define HBYTES 20000                   // per-group H: 50 rows x 400 B

// ============================ helpers ======================================
typedef short bf16x8 __attribute__((ext_vector_type(8)));
typedef float f32x4  __attribute__((ext_vector_type(4)));
typedef unsigned u32x4 __attribute__((ext_vector_type(4)));

__device__ __forceinline__ unsigned short f2bf(float f) {
    unsigned int u = __float_as_uint(f);
    u += 0x7fffu + ((u >> 16) & 1u);          // RNE
    return (unsigned short)(u >> 16);
}
__device__ __forceinline__ float bf2f(short s) {
    return __uint_as_float(((unsigned int)(unsigned short)s) << 16);
}
__device__ __forceinline__ float frcp(float x) { return __builtin_amdgcn_rcpf(x); }
#if __has_builtin(__builtin_amdgcn_exp2f)
__device__ __forceinline__ float fexp2(float x){ return __builtin_amdgcn_exp2f(x); }
#else
__device__ __forceinline__ float fexp2(float x){ return exp2f(x); }
#endif
__device__ __forceinline__ float fsig(float x) { return frcp(1.f + __expf(-x)); }
__device__ __forceinline__ float ftanh(float x){ return 1.f - 2.f*frcp(1.f + __expf(2.f*x)); }

// HW packed f32->bf16 (RNE), 1 inst per 2 values
__device__ __forceinline__ unsigned cvtpk(float lo, float hi) {
    unsigned r;
    asm("v_cvt_pk_bf16_f32 %0, %1, %2" : "=v"(r) : "v"(lo), "v"(hi));
    return r;
}

// async global->LDS, 16B per lane; LDS dst = wave-uniform base + lane*16.
__device__ __forceinline__ void gld16(const void* g, void* l) {
    __builtin_amdgcn_global_load_lds(
        (const __attribute__((address_space(1))) void*)g,
        (__attribute__((address_space(3))) void*)l, 16, 0, 0);
}

// stage one 20,736-B blob with 256 threads: 1296 16B units (5/thread + 16 extra)
__device__ __forceinline__ void stageBlob(char* __restrict__ dst,
                                          const char* __restrict__ src, int tid)
{
    #pragma unroll
    for (int u = 0; u < 5; ++u)
        gld16(src + (size_t)(u * 256 + tid) * 16, dst + (size_t)(u * 256 + tid) * 16);
    if (tid < 16)
        gld16(src + (size_t)(1280 + tid) * 16, dst + (size_t)(1280 + tid) * 16);
}

__device__ __forceinline__ bf16x8 pack8(float4 a, float4 b) {
    u32x4 t;
    t[0] = cvtpk(a.x, a.y); t[1] = cvtpk(a.z, a.w);
    t[2] = cvtpk(b.x, b.y); t[3] = cvtpk(b.z, b.w);
    return __builtin_bit_cast(bf16x8, t);
}

// ============================ P1: weight packing ===========================
// 38 blocks: 0..13 word GRU (dir*7+c), 14..18 word attn, 19..32 sent GRU,
// 33..37 sent attn. GRU bias unit (rows 0..15, byte 400): bR',bZ',bN2,hN2 by
// row group: bR' = -K(bihR+bhhR), bZ' = K(bihZ+bhhZ), bN2 = 2K*bihN,
// hN2 = 2K*bhhN. Attn: rows 0..11 ab2 = 2K*ab; rows 12..23 cx2n = -2*cx.
__global__ void pack_kernel(
    const float* __restrict__ wWf, const float* __restrict__ wbif, const float* __restrict__ wbhf,
    const float* __restrict__ wWb, const float* __restrict__ wbib, const float* __restrict__ wbhb,
    const float* __restrict__ waW, const float* __restrict__ wab, const float* __restrict__ wactx,
    const float* __restrict__ sWf, const float* __restrict__ sbif, const float* __restrict__ sbhf,
    const float* __restrict__ sWb, const float* __restrict__ sbib, const float* __restrict__ sbhb,
    const float* __restrict__ saW, const float* __restrict__ sab, const float* __restrict__ sactx,
    char* __restrict__ ws)
{
    const int b = blockIdx.x, tid = threadIdx.x;
    const bool word = b < 19;
    const int lb = word ? b : b - 19;
    char* blob;
    if (lb < 14) blob = ws + (word ? OFF_PGW : OFF_PGS) + (size_t)lb * BB;
    else         blob = ws + (word ? OFF_PAW : OFF_PAS) + (size_t)(lb - 14) * BB;

    for (int i = tid; i < (int)(BB / 4); i += 256) ((unsigned*)blob)[i] = 0u;
    __syncthreads();

    unsigned short* w16 = (unsigned short*)blob;
    if (lb < 14) {
        const int dir = lb / 7, c = lb % 7;
        const float* W   = word ? (dir ? wWb : wWf) : (dir ? sWb : sWf);
        const float* bih = word ? (dir ? wbib : wbif) : (dir ? sbib : sbif);
        const float* bhh = word ? (dir ? wbhb : wbhf) : (dir ? sbhb : sbhf);
        for (int e = tid; e < 48 * 200; e += 256) {
            const int row = e / 200, k = e - row * 200;
            const int gate = row >> 4, j = c * 16 + (row & 15);
            if (j < NHW) w16[row * 216 + k] = f2bf(W[(size_t)(gate * NHW + j) * ED + k]);
        }
        if (tid < 64) {
            const int sect = tid >> 4, j = c * 16 + (tid & 15);
            float v = 0.f;
            if (j < NHW) {
                if (sect == 0)      v = -KL2E * (bih[j] + bhh[j]);
                else if (sect == 1) v =  KL2E * (bih[NHW + j] + bhh[NHW + j]);
                else if (sect == 2) v = 2.f * KL2E * bih[2 * NHW + j];
                else                v = 2.f * KL2E * bhh[2 * NHW + j];
            }
            ((float*)(blob + (size_t)(tid >> 2) * 432 + 400))[tid & 3] = v;
        }
    } else {
        const int cb = lb - 14;
        const float* W  = word ? waW : saW;
        const float* ab = word ? wab : sab;
        const float* cx = word ? wactx : sactx;
        for (int e = tid; e < 48 * 200; e += 256) {
            const int row = e / 200, k = e - row * 200;
            const int d = cb * 48 + row;
            if (d < FEAT) w16[row * 216 + k] = f2bf(W[(size_t)d * FEAT + k]);
        }
        if (tid < 48) {
            const int d = cb * 48 + tid;
            float ab2 = 0.f, cxn = 0.f;
            if (d < FEAT) { ab2 = 2.f * KL2E * ab[d]; cxn = -2.f * cx[d]; }
            ((float*)(blob + (size_t)(tid >> 2) * 432 + 400))[tid & 3] = ab2;
            ((float*)(blob + (size_t)(12 + (tid >> 2)) * 432 + 400))[tid & 3] = cxn;
        }
    }
}

// ============================ fused HAN stage kernel =======================
// v4: block = 2 groups, 256 thr = 4 waves (2/group, Mt=2). LDS 81,472 B
// (2 staging slots + H[2][50][400]) -> 2 blocks/CU, 16 waves/CU: the second
// resident block overlaps barrier/drain phases (m114). Plain dbuf +
// distance-1 prefetch + __syncthreads (counted-vmcnt proven neutral).
// kc==6 weight reads are q==0 only (q>=1 would read the fp32 bias unit,
// whose bf16 reinterpretation can be NaN -> 0*NaN poisons MFMA).
// sc/al/part alias the H region (dead after each wave's own hf load).
template<bool WORD>
__global__ __launch_bounds__(256, 4) void han_kernel(
    const int* __restrict__ xtok,
    const void* __restrict__ Ain,
    const char* __restrict__ gpk,    // 14 GRU blobs
    const char* __restrict__ apk,    // 5 attn blobs
    const int nvalid,                // 50 / 40
    unsigned short* __restrict__ Out)
{
    __shared__ __align__(16) char smem[2 * SLOT + 2 * HBYTES];   // 81,472
    char* bufs = smem;                           // 2 x 20,736
    char* Hsh  = smem + 2 * SLOT;                // [2][50][400]

    const int tid  = threadIdx.x;
    const int lane = tid & 63, wv = tid >> 6;
    const int sent = wv >> 1, half = wv & 1;
    const int ln15 = lane & 15, q = lane >> 4;
    const long g   = (long)blockIdx.x * 2 + sent;
    char* Hme = Hsh + (size_t)sent * HBYTES;
    // post-loop alias region (rows 0..5 of this group's H, dead by then)
    float* sc_sh = (float*)Hme;                  // 64 f32
    float* al_sh = (float*)(Hme + 256);          // 64 f32
    float* part  = (float*)(Hme + 512);          // [2][224] f32

    // ---- prologue staging: slot 0 ----
    stageBlob(bufs, gpk, tid);

    // ---- A fragments (overlaps staging latency) ----
    bf16x8 af[2][7];
    if (WORD) {
        const float* emb = (const float*)Ain;
        #pragma unroll
        for (int Mt = 0; Mt < 2; ++Mt) {
            const int item = half * 32 + Mt * 16 + ln15;
            int tok = VOCABM1;                       // padding row: all zeros
            if (item < nvalid) tok = xtok[g * nvalid + item];
            const float4* rp = (const float4*)(emb + (long)tok * ED);
            #pragma unroll
            for (int kc = 0; kc < 6; ++kc)
                af[Mt][kc] = pack8(rp[kc * 8 + q * 2], rp[kc * 8 + q * 2 + 1]);
            af[Mt][6] = (q == 0) ? pack8(rp[48], rp[49]) : (bf16x8)(short)0;
        }
    } else {
        const char* sv = (const char*)Ain;
        #pragma unroll
        for (int Mt = 0; Mt < 2; ++Mt) {
            const int item = half * 32 + Mt * 16 + ln15;
            const int ic = item < nvalid ? item : nvalid - 1;
            const char* rp = sv + (g * nvalid + ic) * 400;
            #pragma unroll
            for (int kc = 0; kc < 7; ++kc) {
                bf16x8 v = (bf16x8)(short)0;
                if (item < nvalid && (kc < 6 || q == 0))
                    v = *(const bf16x8*)(rp + kc * 64 + q * 16);
                af[Mt][kc] = v;
            }
        }
    }

    __syncthreads();   // slot 0 resident

    bf16x8 hf[2][7];
    float sacc[2][4] = {{0.f}};

    for (int s = 0; s < 19; ++s) {
        // distance-1 prefetch into the other slot (readers of s-1 are done)
        {
            const int t = (s + 1 <= 18) ? (s + 1) : 18;
            const char* nb = (t < 14) ? gpk + (size_t)t * BB
                                      : apk + (size_t)(t - 14) * BB;
            stageBlob(bufs + (size_t)((s + 1) & 1) * SLOT, nb, tid);
        }
        char* cur = bufs + (size_t)(s & 1) * SLOT;

        if (s < 14) {
            // ---- GRU chunk: units [cc*16, +16) of direction dir ----
            f32x4 a0[2] = {}, a1[2] = {}, a2[2] = {};
            #pragma unroll
            for (int kc = 0; kc < 7; ++kc) {
                bf16x8 b0 = (bf16x8)(short)0, b1 = (bf16x8)(short)0, b2 = (bf16x8)(short)0;
                if (kc < 6 || q == 0) {   // kc==6,q>=1 would hit the bias unit
                    b0 = *(const bf16x8*)(cur + (size_t)(0  + ln15) * 432 + kc * 64 + q * 16);
                    b1 = *(const bf16x8*)(cur + (size_t)(16 + ln15) * 432 + kc * 64 + q * 16);
                    b2 = *(const bf16x8*)(cur + (size_t)(32 + ln15) * 432 + kc * 64 + q * 16);
                }
                #pragma unroll
                for (int Mt = 0; Mt < 2; ++Mt) {
                    a0[Mt] = __builtin_amdgcn_mfma_f32_16x16x32_bf16(b0, af[Mt][kc], a0[Mt], 0, 0, 0);
                    a1[Mt] = __builtin_amdgcn_mfma_f32_16x16x32_bf16(b1, af[Mt][kc], a1[Mt], 0, 0, 0);
                    a2[Mt] = __builtin_amdgcn_mfma_f32_16x16x32_bf16(b2, af[Mt][kc], a2[Mt], 0, 0, 0);
                }
            }
            const int dir = s / 7, cc = s - dir * 7;
            if (cc * 16 + q * 4 < NHW) {
                const f32x4 bR = *(const f32x4*)(cur + (size_t)(0  + q) * 432 + 400);
                const f32x4 bZ = *(const f32x4*)(cur + (size_t)(4  + q) * 432 + 400);
                const f32x4 bN = *(const f32x4*)(cur + (size_t)(8  + q) * 432 + 400);
                const f32x4 hN = *(const f32x4*)(cur + (size_t)(12 + q) * 432 + 400);
                const int ub = dir * NHW + cc * 16 + q * 4;
                #pragma unroll
                for (int Mt = 0; Mt < 2; ++Mt) {
                    const int item = half * 32 + Mt * 16 + ln15;
                    float h[4];
                    #pragma unroll
                    for (int rg = 0; rg < 4; ++rg) {
                        const float r  = frcp(1.f + fexp2(fmaf(a0[Mt][rg], -KL2E, bR[rg])));
                        const float zc = frcp(1.f + fexp2(fmaf(a1[Mt][rg],  KL2E, bZ[rg])));
                        const float t  = frcp(1.f + fexp2(fmaf(a2[Mt][rg], 2.f * KL2E,
                                                  fmaf(r, hN[rg], bN[rg]))));
                        h[rg] = zc * (1.f - 2.f * t);
                    }
                    if (item < nvalid) {
                        uint2 o; o.x = cvtpk(h[0], h[1]); o.y = cvtpk(h[2], h[3]);
                        *(uint2*)(Hme + (size_t)item * HST + ub * 2) = o;
                    }
                }
            }
        } else {
            // ---- attention score chunk ----
            if (s == 14) {   // own-wave rows only; same-wave ds ordering via lgkmcnt
                #pragma unroll
                for (int Mt = 0; Mt < 2; ++Mt) {
                    const int item = half * 32 + Mt * 16 + ln15;
                    #pragma unroll
                    for (int kc = 0; kc < 7; ++kc) {
                        bf16x8 v = (bf16x8)(short)0;
                        if (item < nvalid && (kc < 6 || q == 0))
                            v = *(const bf16x8*)(Hme + (size_t)item * HST + kc * 64 + q * 16);
                        hf[Mt][kc] = v;
                    }
                }
            }
            f32x4 ac[2][3] = {};
            #pragma unroll
            for (int kc = 0; kc < 7; ++kc) {
                bf16x8 b0 = (bf16x8)(short)0, b1 = (bf16x8)(short)0, b2 = (bf16x8)(short)0;
                if (kc < 6 || q == 0) {   // kc==6,q>=1 would hit the bias unit
                    b0 = *(const bf16x8*)(cur + (size_t)(0  + ln15) * 432 + kc * 64 + q * 16);
                    b1 = *(const bf16x8*)(cur + (size_t)(16 + ln15) * 432 + kc * 64 + q * 16);
                    b2 = *(const bf16x8*)(cur + (size_t)(32 + ln15) * 432 + kc * 64 + q * 16);
                }
                #pragma unroll
                for (int Mt = 0; Mt < 2; ++Mt) {
                    ac[Mt][0] = __builtin_amdgcn_mfma_f32_16x16x32_bf16(hf[Mt][kc], b0, ac[Mt][0], 0, 0, 0);
                    ac[Mt][1] = __builtin_amdgcn_mfma_f32_16x16x32_bf16(hf[Mt][kc], b1, ac[Mt][1], 0, 0, 0);
                    ac[Mt][2] = __builtin_amdgcn_mfma_f32_16x16x32_bf16(hf[Mt][kc], b2, ac[Mt][2], 0, 0, 0);
                }
            }
            // tanh(u)·cx folded: sacc += cx2n / (1 + exp2(2K·acc + ab2))
            #pragma unroll
            for (int Nt = 0; Nt < 3; ++Nt) {
                const int bo = 4 * (Nt * 16 + ln15);
                const float ab2 = *(const float*)(cur + (size_t)(bo >> 4) * 432 + 400 + (bo & 15));
                const int co = 192 + bo;
                const float cxn = *(const float*)(cur + (size_t)(co >> 4) * 432 + 400 + (co & 15));
                #pragma unroll
                for (int Mt = 0; Mt < 2; ++Mt)
                    #pragma unroll
                    for (int rg = 0; rg < 4; ++rg) {
                        const float u = frcp(1.f + fexp2(fmaf(ac[Mt][Nt][rg], 2.f * KL2E, ab2)));
                        sacc[Mt][rg] = fmaf(u, cxn, sacc[Mt][rg]);
                    }
            }
        }
        __syncthreads();
    }

    // ---- reduce scores over the 16 d-lanes; park per word-row ----
    #pragma unroll
    for (int Mt = 0; Mt < 2; ++Mt)
        #pragma unroll
        for (int rg = 0; rg < 4; ++rg) {
            float v = sacc[Mt][rg];
            v += __shfl_xor(v, 1); v += __shfl_xor(v, 2);
            v += __shfl_xor(v, 4); v += __shfl_xor(v, 8);
            sacc[Mt][rg] = v;
        }
    // H region is dead (all waves past their s==14 hf load, final loop barrier
    // retired) -> sc/al/part alias is safe from here.
    if (ln15 == 0) {
        #pragma unroll
        for (int Mt = 0; Mt < 2; ++Mt)
            #pragma unroll
            for (int rg = 0; rg < 4; ++rg)
                sc_sh[half * 32 + Mt * 16 + q * 4 + rg] = sacc[Mt][rg];
    }
    __syncthreads();

    // ---- per-group softmax over 64 padded rows (exp2-scaled) ----
    {
        const float sv0 = (lane < nvalid) ? sc_sh[lane] : -1e30f;
        float m = sv0;
        m = fmaxf(m, __shfl_xor(m, 1));  m = fmaxf(m, __shfl_xor(m, 2));
        m = fmaxf(m, __shfl_xor(m, 4));  m = fmaxf(m, __shfl_xor(m, 8));
        m = fmaxf(m, __shfl_xor(m, 16)); m = fmaxf(m, __shfl_xor(m, 32));
        const float e = (lane < nvalid) ? fexp2((sv0 - m) * KL2E) : 0.f;
        float ss = e;
        ss += __shfl_xor(ss, 1);  ss += __shfl_xor(ss, 2);
        ss += __shfl_xor(ss, 4);  ss += __shfl_xor(ss, 8);
        ss += __shfl_xor(ss, 16); ss += __shfl_xor(ss, 32);
        if (half == 0) al_sh[lane] = e * frcp(ss);
    }
    __syncthreads();

    // ---- pooling straight from hf fragments ----
    {
        const float aM0 = al_sh[half * 32 + ln15];
        const float aM1 = al_sh[half * 32 + 16 + ln15];
        #pragma unroll
        for (int kc = 0; kc < 7; ++kc) {
            float p[8];
            #pragma unroll
            for (int j = 0; j < 8; ++j)
                p[j] = aM0 * bf2f(hf[0][kc][j]) + aM1 * bf2f(hf[1][kc][j]);
            #pragma unroll
            for (int j = 0; j < 8; ++j) {
                p[j] += __shfl_xor(p[j], 1); p[j] += __shfl_xor(p[j], 2);
                p[j] += __shfl_xor(p[j], 4); p[j] += __shfl_xor(p[j], 8);
            }
            if (ln15 == 0) {
                float* dst = part + (size_t)half * 224 + kc * 32 + q * 8;
                f32x4 v0 = {p[0], p[1], p[2], p[3]};
                f32x4 v1 = {p[4], p[5], p[6], p[7]};
                *(f32x4*)dst = v0; *(f32x4*)(dst + 4) = v1;
            }
        }
    }
    __syncthreads();

    // ---- combine halves, write pooled bf16 rows ----
    if (tid < 100) {
        const int sl = tid / 50, i = tid - sl * 50;     // i*4 = k0 < 200
        const float* pg = (const float*)(Hsh + (size_t)sl * HBYTES + 512);
        const float* pa = pg;
        const float* pb = pg + 224;
        uint2 o;
        o.x = cvtpk(pa[i * 4 + 0] + pb[i * 4 + 0], pa[i * 4 + 1] + pb[i * 4 + 1]);
        o.y = cvtpk(pa[i * 4 + 2] + pb[i * 4 + 2], pa[i * 4 + 3] + pb[i * 4 + 3]);
        *(uint2*)(Out + ((long)blockIdx.x * 2 + sl) * 200 + i * 4) = o;
    }
}

// ============================ classifier + log_softmax =====================
__global__ void cls_kernel(const unsigned short* __restrict__ dvec,
                           const float* __restrict__ fcW, const float* __restrict__ fcb,
                           float* __restrict__ out)
{
    const int doc = blockIdx.x, lane = threadIdx.x;  // 64 threads
    const int c = lane & 15, part = lane >> 4;
    const int cs = (c < NC) ? c : 0;
    float acc = (part == 0 && c < NC) ? fcb[c] : 0.f;
    for (int i = 0; i < 50; ++i) {
        const int k = part * 50 + i;
        const float a = bf2f((short)dvec[(size_t)doc * 200 + k]);
        acc += a * ((c < NC) ? fcW[(size_t)cs * 200 + k] : 0.f);
    }
    acc += __shfl_xor(acc, 16); acc += __shfl_xor(acc, 32);
    const float lg = (c < NC) ? acc : -1e30f;
    float m = lg;
    m = fmaxf(m, __shfl_xor(m, 1)); m = fmaxf(m, __shfl_xor(m, 2));
    m = fmaxf(m, __shfl_xor(m, 4)); m = fmaxf(m, __shfl_xor(m, 8));
    const float e = (c < NC) ? __expf(lg - m) : 0.f;
    float ss = e;
    ss += __shfl_xor(ss, 1); ss += __shfl_xor(ss, 2);
    ss += __shfl_xor(ss, 4); ss += __shfl_xor(ss, 8);
    const float lse = m + __logf(ss);
    if (lane < NC) out[(size_t)doc * NC + lane] = lg - lse;
}

// ======================================================================
// Fallback fp32 path — used only if ws_size < WS_NEED.
// ======================================================================
template<int NWRD, int WT>
__device__ __forceinline__ void encode_block(
    float* __restrict__ e_sh, float* __restrict__ h_sh, float* __restrict__ sc_sh,
    const float* __restrict__ Wf, const float* __restrict__ bihf, const float* __restrict__ bhhf,
    const float* __restrict__ Wb, const float* __restrict__ bihb, const float* __restrict__ bhhb,
    const float* __restrict__ aW, const float* __restrict__ ab, const float* __restrict__ actx,
    int tid)
{
    constexpr int WG = NWRD / WT;
    for (int item = tid; item < FEAT * WG; item += 256) {
        const int unit = item % FEAT, wg = item / FEAT;
        const int dir = unit / NHW, j = unit - dir * NHW;
        const float* Wd  = dir ? Wb : Wf;
        const float* bih = dir ? bihb : bihf;
        const float* bhh = dir ? bhhb : bhhf;
        const float4* rowR = (const float4*)(Wd + (size_t)j * ED);
        const float4* rowZ = (const float4*)(Wd + (size_t)(NHW + j) * ED);
        const float4* rowN = (const float4*)(Wd + (size_t)(2 * NHW + j) * ED);
        float aR[WT], aZ[WT], aN[WT];
        #pragma unroll
        for (int t = 0; t < WT; ++t) { aR[t] = 0.f; aZ[t] = 0.f; aN[t] = 0.f; }
        const int w0 = wg * WT;
        #pragma unroll 1
        for (int k4 = 0; k4 < ED / 4; ++k4) {
            const float4 wr = rowR[k4], wz = rowZ[k4], wn = rowN[k4];
            #pragma unroll
            for (int t = 0; t < WT; ++t) {
                const float4 e = *(const float4*)(e_sh + (w0 + t) * ED + k4 * 4);
                aR[t] += wr.x*e.x + wr.y*e.y + wr.z*e.z + wr.w*e.w;
                aZ[t] += wz.x*e.x + wz.y*e.y + wz.z*e.z + wz.w*e.w;
                aN[t] += wn.x*e.x + wn.y*e.y + wn.z*e.z + wn.w*e.w;
            }
        }
        const float bR = bih[j] + bhh[j], bZ = bih[NHW+j] + bhh[NHW+j];
        const float bN = bih[2*NHW+j], hN = bhh[2*NHW+j];
        #pragma unroll
        for (int t = 0; t < WT; ++t) {
            const float r = fsig(aR[t] + bR), z = fsig(aZ[t] + bZ);
            const float n = ftanh(aN[t] + bN + r * hN);
            h_sh[(w0 + t) * FEAT + unit] = (1.f - z) * n;
        }
    }
    __syncthreads();
    for (int item = tid; item < FEAT * WG; item += 256) {
        const int d = item % FEAT, wg = item / FEAT;
        const float4* row = (const float4*)(aW + (size_t)d * FEAT);
        float acc[WT];
        #pragma unroll
        for (int t = 0; t < WT; ++t) acc[t] = 0.f;
        const int w0 = wg * WT;
        #pragma unroll 1
        for (int k4 = 0; k4 < FEAT / 4; ++k4) {
            const float4 wv = row[k4];
            #pragma unroll
            for (int t = 0; t < WT; ++t) {
                const float4 h = *(const float4*)(h_sh + (w0 + t) * FEAT + k4 * 4);
                acc[t] += wv.x*h.x + wv.y*h.y + wv.z*h.z + wv.w*h.w;
            }
        }
        const float bb = ab[d], cc = actx[d];
        #pragma unroll
        for (int t = 0; t < WT; ++t)
            e_sh[d * NWRD + (w0 + t)] = ftanh(acc[t] + bb) * cc;
    }
    __syncthreads();
    if (tid < NWRD) {
        float s = 0.f;
        for (int d = 0; d < FEAT; ++d) s += e_sh[d * NWRD + tid];
        sc_sh[tid] = s;
    }
    __syncthreads();
    if (tid == 0) {
        float m = -1e30f;
        for (int w = 0; w < NWRD; ++w) m = fmaxf(m, sc_sh[w]);
        float s = 0.f;
        for (int w = 0; w < NWRD; ++w) { const float ev = __expf(sc_sh[w] - m); sc_sh[w] = ev; s += ev; }
        const float inv = 1.f / s;
        for (int w = 0; w < NWRD; ++w) sc_sh[w] *= inv;
    }
    __syncthreads();
}

__global__ __launch_bounds__(256) void word_kernel_f32(
    const int* __restrict__ x, const float* __restrict__ emb,
    const float* __restrict__ Wf, const float* __restrict__ bihf, const float* __restrict__ bhhf,
    const float* __restrict__ Wb, const float* __restrict__ bihb, const float* __restrict__ bhhb,
    const float* __restrict__ waW, const float* __restrict__ wab, const float* __restrict__ wactx,
    float* __restrict__ svec)
{
    __shared__ __align__(16) float e_sh[NW * ED];
    __shared__ __align__(16) float h_sh[NW * FEAT];
    __shared__ float sc_sh[NW];
    const int sent = blockIdx.x, tid = threadIdx.x;
    const int* xr = x + (size_t)sent * NW;
    for (int i = tid * 4; i < NW * ED; i += 256 * 4) {
        const int w = i / ED, k = i - w * ED;
        *(float4*)(e_sh + i) = *(const float4*)(emb + (size_t)xr[w] * ED + k);
    }
    __syncthreads();
    encode_block<NW, 25>(e_sh, h_sh, sc_sh, Wf, bihf, bhhf, Wb, bihb, bhhb, waW, wab, wactx, tid);
    if (tid < FEAT) {
        float a = 0.f;
        #pragma unroll 1
        for (int w = 0; w < NW; ++w) a += sc_sh[w] * h_sh[w * FEAT + tid];
        svec[(size_t)sent * FEAT + tid] = a;
    }
}

__global__ __launch_bounds__(256) void sent_kernel_f32(
    const float* __restrict__ svec,
    const float* __restrict__ Wf, const float* __restrict__ bihf, const float* __restrict__ bhhf,
    const float* __restrict__ Wb, const float* __restrict__ bihb, const float* __restrict__ bhhb,
    const float* __restrict__ saW, const float* __restrict__ sab, const float* __restrict__ sactx,
    const float* __restrict__ fcW, const float* __restrict__ fcb,
    float* __restrict__ out)
{
    __shared__ __align__(16) float e_sh[NS * ED];
    __shared__ __align__(16) float h_sh[NS * FEAT];
    __shared__ float sc_sh[NS];
    __shared__ float dvec_sh[FEAT];
    __shared__ float logit_sh[NC];
    __shared__ float lse_sh;
    const int b = blockIdx.x, tid = threadIdx.x;
    const float* src = svec + (size_t)b * NS * FEAT;
    for (int i = tid * 4; i < NS * FEAT; i += 256 * 4)
        *(float4*)(e_sh + i) = *(const float4*)(src + i);
    __syncthreads();
    encode_block<NS, 20>(e_sh, h_sh, sc_sh, Wf, bihf, bhhf, Wb, bihb, bhhb, saW, sab, sactx, tid);
    if (tid < FEAT) {
        float a = 0.f;
        #pragma unroll 1
        for (int s = 0; s < NS; ++s) a += sc_sh[s] * h_sh[s * FEAT + tid];
        dvec_sh[tid] = a;
    }
    __syncthreads();
    if (tid < NC) {
        float a = fcb[tid];
        const float* row = fcW + (size_t)tid * FEAT;
        for (int k = 0; k < FEAT; ++k) a += row[k] * dvec_sh[k];
        logit_sh[tid] = a;
    }
    __syncthreads();
    if (tid == 0) {
        float m = -1e30f;
        for (int c = 0; c < NC; ++c) m = fmaxf(m, logit_sh[c]);
        float s = 0.f;
        for (int c = 0; c < NC; ++c) s += __expf(logit_sh[c] - m);
        lse_sh = m + logf(s);
    }
    __syncthreads();
    if (tid < NC) out[(size_t)b * NC + tid] = logit_sh[tid] - lse_sh;
}

// ============================ launch =======================================
extern "C" void kernel_launch(void* const* d_in, const int* in_sizes, int n_in,
                              void* d_out, int out_size, void* d_ws, size_t ws_size,
                              hipStream_t stream)
{
    const int*   x     = (const int*)d_in[0];
    const float* emb   = (const float*)d_in[1];
    const float* wWf   = (const float*)d_in[2];
    const float* wbif  = (const float*)d_in[3];
    const float* wbhf  = (const float*)d_in[4];
    const float* wWb   = (const float*)d_in[5];
    const float* wbib  = (const float*)d_in[6];
    const float* wbhb  = (const float*)d_in[7];
    const float* waW   = (const float*)d_in[8];
    const float* wab   = (const float*)d_in[9];
    const float* wactx = (const float*)d_in[10];
    const float* sWf   = (const float*)d_in[11];
    const float* sbif  = (const float*)d_in[12];
    const float* sbhf  = (const float*)d_in[13];
    const float* sWb   = (const float*)d_in[14];
    const float* sbib  = (const float*)d_in[15];
    const float* sbhb  = (const float*)d_in[16];
    const float* saW   = (const float*)d_in[17];
    const float* sab   = (const float*)d_in[18];
    const float* sactx = (const float*)d_in[19];
    const float* fcW   = (const float*)d_in[20];
    const float* fcb   = (const float*)d_in[21];
    float* out = (float*)d_out;

    if (ws_size < WS_NEED) {
        float* svec = (float*)d_ws;
        word_kernel_f32<<<NB * NS, 256, 0, stream>>>(
            x, emb, wWf, wbif, wbhf, wWb, wbib, wbhb, waW, wab, wactx, svec);
        sent_kernel_f32<<<NB, 256, 0, stream>>>(
            svec, sWf, sbif, sbhf, sWb, sbib, sbhb, saW, sab, sactx, fcW, fcb, out);
        return;
    }

    char* ws = (char*)d_ws;
    unsigned short* svec = (unsigned short*)(ws + OFF_SV);
    unsigned short* dvec = (unsigned short*)(ws + OFF_DV);

    pack_kernel<<<38, 256, 0, stream>>>(
        wWf, wbif, wbhf, wWb, wbib, wbhb, waW, wab, wactx,
        sWf, sbif, sbhf, sWb, sbib, sbhb, saW, sab, sactx, ws);

    // word stage: 5120 sentences / 2 per block
    han_kernel<true><<<NB * NS / 2, 256, 0, stream>>>(
        x, emb, ws + OFF_PGW, ws + OFF_PAW, NW, svec);

    // sentence stage: 128 docs / 2 per block
    han_kernel<false><<<NB / 2, 256, 0, stream>>>(
        nullptr, svec, ws + OFF_PGS, ws + OFF_PAS, NS, dvec);

    cls_kernel<<<NB, 64, 0, stream>>>(dvec, fcW, fcb, out);
}